// Round 2
// baseline (1872.838 us; speedup 1.0000x reference)
//
#include <hip/hip_runtime.h>
#include <hip/hip_bf16.h>
#include <math.h>

typedef short bf16x8 __attribute__((ext_vector_type(8)));
typedef float f32x4 __attribute__((ext_vector_type(4)));
typedef unsigned int u32;

#define NROWS 131072
#define DDIM 224
#define HREAL 400
#define HP 416          // padded hidden dim (13*32)
#define ZDIM 4
#define ROWS 64         // rows per block
#define ASTRIDE 1664    // HP * 4 bytes (u32 per element: lo<<16|hi)

// ---- workspace layout (bytes) ----
#define OFF_W1H   0          // bf16 [416][224]
#define OFF_W1L   186368
#define OFF_W2H   372736     // bf16 [416][416]
#define OFF_W2L   718848
#define OFF_W5H   1064960
#define OFF_W5L   1411072
#define OFF_W6H   1757184    // bf16 [224][416]
#define OFF_W6L   1943552
#define OFF_C     2129920    // f32 scalar ||d||
#define OFF_MSEP  2129936    // f32 [2048]
#define OFF_DEFEN 2138128    // f32 [131072]
#define OFF_CAND  2662416    // f32 [1280]
// total 2667536 bytes

#define LDS_ACT   0                 // [64][416] u32 (lo<<16|hi), xor-swizzled
#define LDS_ZBUF  106496            // [64][4] f32
#define LDS_RED   107520            // [64][2][4] f32
#define LDS_TOTAL 109568

__device__ __forceinline__ unsigned short f2bf(float v) {
  union { float f; u32 u; } a; a.f = v;
  u32 u = a.u;
  u += 0x7fffu + ((u >> 16) & 1u);   // round-to-nearest-even
  return (unsigned short)(u >> 16);
}
__device__ __forceinline__ float bf2f(unsigned short h) {
  union { u32 u; float f; } a; a.u = ((u32)h) << 16; return a.f;
}
__device__ __forceinline__ u32 packsplit(float v) {
  unsigned short hi = f2bf(v);
  unsigned short lo = f2bf(v - bf2f(hi));
  return ((u32)lo << 16) | (u32)hi;
}

// ---------------- prep: transpose+pad+split weights, ||d|| ----------------
__global__ void k_prep(const float* __restrict__ We1, const float* __restrict__ We2,
                       const float* __restrict__ Wd2, const float* __restrict__ Wd3,
                       const float* __restrict__ dvec,
                       unsigned short* __restrict__ W1h, unsigned short* __restrict__ W1l,
                       unsigned short* __restrict__ W2h, unsigned short* __restrict__ W2l,
                       unsigned short* __restrict__ W5h, unsigned short* __restrict__ W5l,
                       unsigned short* __restrict__ W6h, unsigned short* __restrict__ W6l,
                       float* __restrict__ Cout) {
  const int t = blockIdx.x * 256 + threadIdx.x;
  const int NT = gridDim.x * 256;
  for (int i = t; i < HP * DDIM; i += NT) {           // W1t[n][k] = We1[k][n]
    int n = i / DDIM, k = i - n * DDIM;
    float w = (n < HREAL) ? We1[k * HREAL + n] : 0.f;
    unsigned short h = f2bf(w);
    W1h[i] = h; W1l[i] = f2bf(w - bf2f(h));
  }
  for (int i = t; i < HP * HP; i += NT) {             // W2t[n][k] = We2[k][n]
    int n = i / HP, k = i - n * HP;
    float w = (n < HREAL && k < HREAL) ? We2[k * HREAL + n] : 0.f;
    unsigned short h = f2bf(w);
    W2h[i] = h; W2l[i] = f2bf(w - bf2f(h));
  }
  for (int i = t; i < HP * HP; i += NT) {             // W5t[n][k] = Wd2[k][n]
    int n = i / HP, k = i - n * HP;
    float w = (n < HREAL && k < HREAL) ? Wd2[k * HREAL + n] : 0.f;
    unsigned short h = f2bf(w);
    W5h[i] = h; W5l[i] = f2bf(w - bf2f(h));
  }
  for (int i = t; i < DDIM * HP; i += NT) {           // W6t[n][k] = Wd3[k][n]
    int n = i / HP, k = i - n * HP;
    float w = (k < HREAL) ? Wd3[k * DDIM + n] : 0.f;
    unsigned short h = f2bf(w);
    W6h[i] = h; W6l[i] = f2bf(w - bf2f(h));
  }
  if (blockIdx.x == 0) {
    float s = 0.f;
    for (int i = threadIdx.x; i < DDIM; i += 256) { float v = dvec[i]; s += v * v; }
#pragma unroll
    for (int off = 1; off < 64; off <<= 1) s += __shfl_xor(s, off);
    __shared__ float cs[4];
    if ((threadIdx.x & 63) == 0) cs[threadIdx.x >> 6] = s;
    __syncthreads();
    if (threadIdx.x == 0) Cout[0] = sqrtf(cs[0] + cs[1] + cs[2] + cs[3]);
  }
}

union U8 { bf16x8 v; u32 w[4]; };

__device__ __forceinline__ void unpack8(uint4 p, uint4 q, bf16x8& hi, bf16x8& lo) {
  U8 h, l;
  h.w[0] = (p.x & 0xffffu) | (p.y << 16);
  h.w[1] = (p.z & 0xffffu) | (p.w << 16);
  h.w[2] = (q.x & 0xffffu) | (q.y << 16);
  h.w[3] = (q.z & 0xffffu) | (q.w << 16);
  l.w[0] = (p.x >> 16) | (p.y & 0xffff0000u);
  l.w[1] = (p.z >> 16) | (p.w & 0xffff0000u);
  l.w[2] = (q.x >> 16) | (q.w & 0xffff0000u & 0xffff0000u ? (p.w & 0u) : 0u); // placeholder (fixed below)
  l.w[2] = (q.x >> 16) | (q.y & 0xffff0000u);
  l.w[3] = (q.z >> 16) | (q.w & 0xffff0000u);
  hi = h.v; lo = l.v;
}

// ---------------- fused MLP layer: act(LDS) @ Wt + b -> lrelu -> act(LDS) -------
// 8 waves = 4 M-waves (16 rows each) x 2 N-waves (NFRAG*16 cols each)
template <int KP, int NFRAG>
__device__ __forceinline__ void mfma_layer(char* actb,
                                           const unsigned short* __restrict__ Wh,
                                           const unsigned short* __restrict__ Wl,
                                           const float* __restrict__ bias, int realN,
                                           int m0, int nwave, int l15, int g) {
  f32x4 acc[NFRAG] = {};
  const int n0 = nwave * (NFRAG * 16);
  const int arow = m0 + l15;
  const char* abase = actb + arow * ASTRIDE;
  const int swz = (arow & 7) << 4;
  for (int ks = 0; ks < KP / 32; ++ks) {
    const int b0 = ks * 128 + g * 32;
    uint4 p = *(const uint4*)(abase + (b0 ^ swz));
    uint4 q = *(const uint4*)(abase + ((b0 + 16) ^ swz));
    bf16x8 ah, al;
    unpack8(p, q, ah, al);
#pragma unroll
    for (int nf = 0; nf < NFRAG; ++nf) {
      const unsigned short* wp = Wh + (size_t)(n0 + nf * 16 + l15) * KP + ks * 32 + g * 8;
      const unsigned short* wq = Wl + (size_t)(n0 + nf * 16 + l15) * KP + ks * 32 + g * 8;
      const bf16x8 bh = *(const bf16x8*)wp;
      const bf16x8 bl = *(const bf16x8*)wq;
      acc[nf] = __builtin_amdgcn_mfma_f32_16x16x32_bf16(ah, bh, acc[nf], 0, 0, 0);
      acc[nf] = __builtin_amdgcn_mfma_f32_16x16x32_bf16(al, bh, acc[nf], 0, 0, 0);
      acc[nf] = __builtin_amdgcn_mfma_f32_16x16x32_bf16(ah, bl, acc[nf], 0, 0, 0);
    }
  }
  __syncthreads();   // everyone done reading act
#pragma unroll
  for (int nf = 0; nf < NFRAG; ++nf) {
    const int col = n0 + nf * 16 + l15;
    const float bv = (col < realN) ? bias[col] : 0.0f;
#pragma unroll
    for (int j = 0; j < 4; ++j) {
      const int row = m0 + g * 4 + j;
      float v = acc[nf][j] + bv;
      v = fmaxf(v, 0.1f * v);   // leaky relu
      *(u32*)(actb + row * ASTRIDE + ((col * 4) ^ ((row & 7) << 4))) = packsplit(v);
    }
  }
  __syncthreads();
}

// ---------------- main fused kernel: 64 rows per block ----------------
__global__ __launch_bounds__(512, 1) void k_main(
    const float* __restrict__ xin, const float* __restrict__ dvec,
    const float* __restrict__ be1, const float* __restrict__ be2, const float* __restrict__ be3,
    const float* __restrict__ bd1, const float* __restrict__ bd2, const float* __restrict__ bd3,
    const float* __restrict__ We3, const float* __restrict__ Wd1,
    const unsigned short* __restrict__ W1h, const unsigned short* __restrict__ W1l,
    const unsigned short* __restrict__ W2h, const unsigned short* __restrict__ W2l,
    const unsigned short* __restrict__ W5h, const unsigned short* __restrict__ W5l,
    const unsigned short* __restrict__ W6h, const unsigned short* __restrict__ W6l,
    const float* __restrict__ Cptr,
    float* __restrict__ y_out, float* __restrict__ z_out,
    float* __restrict__ defen, float* __restrict__ msep) {
  extern __shared__ __align__(16) char lds[];
  char* actb = lds + LDS_ACT;
  float* zbuf = (float*)(lds + LDS_ZBUF);
  float* red  = (float*)(lds + LDS_RED);

  const int tid = threadIdx.x;
  const int lane = tid & 63;
  const int wid = tid >> 6;       // 0..7
  const int m0 = (wid >> 1) * 16; // 4 M-waves, 16 rows each
  const int nwave = wid & 1;      // 2 N-waves
  const int l15 = lane & 15;
  const int g = lane >> 4;        // 0..3
  const int row0 = blockIdx.x * ROWS;

  // ---- stage x -> act (split bf16 pair, swizzled) ----
  for (int i = 0; i < 28; ++i) {
    int f = i * 512 + tid;                       // 0 .. 14335
    int r = f / DDIM, c = f - r * DDIM;
    float v = xin[(size_t)(row0 + r) * DDIM + c];
    *(u32*)(actb + r * ASTRIDE + ((c * 4) ^ ((r & 7) << 4))) = packsplit(v);
  }
  __syncthreads();

  // ---- L1: x(224) -> h1(400), L2: h1 -> h2(400) ----
  mfma_layer<DDIM, 13>(actb, W1h, W1l, be1, HREAL, m0, nwave, l15, g);
  mfma_layer<HP, 13>(actb, W2h, W2l, be2, HREAL, m0, nwave, l15, g);

  // ---- L3: z = h2 @ We3 + be3 (Z=4), f32 ----
  if (tid < 256) {
    const int r = tid >> 2, j = tid & 3;
    const char* abase = actb + r * ASTRIDE;
    const int swz = (r & 7) << 4;
    float s = 0.f;
    for (int k = 0; k < HREAL; k += 8) {
      uint4 p = *(const uint4*)(abase + ((k * 4) ^ swz));
      uint4 q = *(const uint4*)(abase + ((k * 4 + 16) ^ swz));
      u32 e[8] = {p.x, p.y, p.z, p.w, q.x, q.y, q.z, q.w};
#pragma unroll
      for (int u = 0; u < 8; ++u) {
        float h = bf2f((unsigned short)(e[u] & 0xffffu)) + bf2f((unsigned short)(e[u] >> 16));
        s = fmaf(h, We3[(k + u) * 4 + j], s);
      }
    }
    s += be3[j];
    z_out[(size_t)(row0 + r) * 4 + j] = s;
    zbuf[r * 4 + j] = s;
  }
  __syncthreads();

  // ---- L4: g1 = lrelu(z @ Wd1 + bd1) -> act, f32 ----
  {
    const int r = tid >> 3, q = tid & 7;
    const float z0 = zbuf[r * 4 + 0], z1 = zbuf[r * 4 + 1];
    const float z2 = zbuf[r * 4 + 2], z3 = zbuf[r * 4 + 3];
    char* abase = actb + r * ASTRIDE;
    const int swz = (r & 7) << 4;
    for (int c = q * 52; c < q * 52 + 52; ++c) {
      float v = 0.f;
      if (c < HREAL) {
        v = fmaf(z0, Wd1[c], fmaf(z1, Wd1[HREAL + c], fmaf(z2, Wd1[2 * HREAL + c], fmaf(z3, Wd1[3 * HREAL + c], bd1[c]))));
        v = fmaxf(v, 0.1f * v);
      }
      *(u32*)(abase + ((c * 4) ^ swz)) = packsplit(v);
    }
  }
  __syncthreads();

  // ---- L5: g2 = lrelu(g1 @ Wd2 + bd2) ----
  mfma_layer<HP, 13>(actb, W5h, W5l, bd2, HREAL, m0, nwave, l15, g);

  // ---- L6: y = tanh(g2 @ Wd3 + bd3) + fused reductions ----
  {
    f32x4 acc[7] = {};
    const int n0 = nwave * 112;
    const int arow = m0 + l15;
    const char* abase = actb + arow * ASTRIDE;
    const int swz = (arow & 7) << 4;
    for (int ks = 0; ks < HP / 32; ++ks) {
      const int b0 = ks * 128 + g * 32;
      uint4 p = *(const uint4*)(abase + (b0 ^ swz));
      uint4 q = *(const uint4*)(abase + ((b0 + 16) ^ swz));
      bf16x8 ah, al;
      unpack8(p, q, ah, al);
#pragma unroll
      for (int nf = 0; nf < 7; ++nf) {
        const unsigned short* wp = W6h + (size_t)(n0 + nf * 16 + l15) * HP + ks * 32 + g * 8;
        const unsigned short* wq = W6l + (size_t)(n0 + nf * 16 + l15) * HP + ks * 32 + g * 8;
        const bf16x8 bh = *(const bf16x8*)wp;
        const bf16x8 bl = *(const bf16x8*)wq;
        acc[nf] = __builtin_amdgcn_mfma_f32_16x16x32_bf16(ah, bh, acc[nf], 0, 0, 0);
        acc[nf] = __builtin_amdgcn_mfma_f32_16x16x32_bf16(al, bh, acc[nf], 0, 0, 0);
        acc[nf] = __builtin_amdgcn_mfma_f32_16x16x32_bf16(ah, bl, acc[nf], 0, 0, 0);
      }
    }
#pragma unroll
    for (int j = 0; j < 4; ++j) {
      const int lrow = m0 + g * 4 + j;
      const int grow = row0 + lrow;
      float pA = 0.f, pB = 0.f, pM = 0.f;
#pragma unroll
      for (int nf = 0; nf < 7; ++nf) {
        const int col = n0 + nf * 16 + l15;
        float v = acc[nf][j] + bd3[col];
        float y = tanhf(v);
        y_out[(size_t)grow * DDIM + col] = y;
        float dv = dvec[col];
        float xv = xin[(size_t)grow * DDIM + col];
        pA = fmaf(y, dv, pA);
        pB = fmaf(y, y, pB);
        float df = y - xv;
        pM = fmaf(df, df, pM);
      }
#pragma unroll
      for (int off = 1; off < 16; off <<= 1) {
        pA += __shfl_xor(pA, off);
        pB += __shfl_xor(pB, off);
        pM += __shfl_xor(pM, off);
      }
      if (l15 == 0) {
        float* rr = &red[(lrow * 2 + nwave) * 4];
        rr[0] = pA; rr[1] = pB; rr[2] = pM;
      }
    }
  }
  __syncthreads();

  if (tid < 64) {
    const float Cn = Cptr[0];
    const int r = tid;
    float A  = red[(r * 2 + 0) * 4 + 0] + red[(r * 2 + 1) * 4 + 0];
    float B2 = red[(r * 2 + 0) * 4 + 1] + red[(r * 2 + 1) * 4 + 1];
    float Mloc = red[(r * 2 + 0) * 4 + 2] + red[(r * 2 + 1) * 4 + 2];
    defen[row0 + r] = A / (sqrtf(B2) * Cn + 1e-5f);
#pragma unroll
    for (int off = 1; off < 64; off <<= 1) Mloc += __shfl_xor(Mloc, off);
    if (tid == 0) msep[blockIdx.x] = Mloc;
  }
}

// ---------------- top-k stage A: 64 blocks, per-block top-20 of 2048 ----------------
__global__ void k_topk_a(const float* __restrict__ defen, float* __restrict__ cand) {
  __shared__ float vals[2048];
  __shared__ float wv[4];
  __shared__ int wi[4];
  const int tid = threadIdx.x;
  const int base = blockIdx.x * 2048;
  for (int i = tid; i < 2048; i += 256) vals[i] = defen[base + i];
  __syncthreads();
  for (int it = 0; it < 20; ++it) {
    float mv = -1e30f; int mi = 1 << 30;
    for (int i = tid; i < 2048; i += 256) {
      float v = vals[i];
      if (v > mv) { mv = v; mi = i; }
    }
#pragma unroll
    for (int off = 1; off < 64; off <<= 1) {
      float ov = __shfl_xor(mv, off); int oi = __shfl_xor(mi, off);
      if (ov > mv || (ov == mv && oi < mi)) { mv = ov; mi = oi; }
    }
    if ((tid & 63) == 0) { wv[tid >> 6] = mv; wi[tid >> 6] = mi; }
    __syncthreads();
    if (tid == 0) {
      float bv = wv[0]; int bi = wi[0];
      for (int q = 1; q < 4; ++q)
        if (wv[q] > bv || (wv[q] == bv && wi[q] < bi)) { bv = wv[q]; bi = wi[q]; }
      cand[blockIdx.x * 20 + it] = bv;
      vals[bi] = -1e30f;
    }
    __syncthreads();
  }
}

// ---------------- top-k stage B: final top-20 of 1280 + R_loss ----------------
__global__ void k_topk_b(const float* __restrict__ cand, const float* __restrict__ msep,
                         float* __restrict__ rloss) {
  __shared__ float vals[1280];
  __shared__ float wv[4];
  __shared__ int wi[4];
  __shared__ float msum[4];
  const int tid = threadIdx.x;
  for (int i = tid; i < 1280; i += 256) vals[i] = cand[i];
  float ms = 0.f;
  for (int i = tid; i < 2048; i += 256) ms += msep[i];
#pragma unroll
  for (int off = 1; off < 64; off <<= 1) ms += __shfl_xor(ms, off);
  if ((tid & 63) == 0) msum[tid >> 6] = ms;
  __syncthreads();
  float sam = 0.f;
  for (int it = 0; it < 20; ++it) {
    float mv = -1e30f; int mi = 1 << 30;
    for (int i = tid; i < 1280; i += 256) {
      float v = vals[i];
      if (v > mv) { mv = v; mi = i; }
    }
#pragma unroll
    for (int off = 1; off < 64; off <<= 1) {
      float ov = __shfl_xor(mv, off); int oi = __shfl_xor(mi, off);
      if (ov > mv || (ov == mv && oi < mi)) { mv = ov; mi = oi; }
    }
    if ((tid & 63) == 0) { wv[tid >> 6] = mv; wi[tid >> 6] = mi; }
    __syncthreads();
    if (tid == 0) {
      float bv = wv[0]; int bi = wi[0];
      for (int q = 1; q < 4; ++q)
        if (wv[q] > bv || (wv[q] == bv && wi[q] < bi)) { bv = wv[q]; bi = wi[q]; }
      sam += bv;
      vals[bi] = -1e30f;
    }
    __syncthreads();
  }
  if (tid == 0) {
    float mse = (msum[0] + msum[1] + msum[2] + msum[3]) / 29360128.f;  // N*D
    rloss[0] = mse + 0.1f * sam;
  }
}

extern "C" void kernel_launch(void* const* d_in, const int* in_sizes, int n_in,
                              void* d_out, int out_size, void* d_ws, size_t ws_size,
                              hipStream_t stream) {
  const float* x    = (const float*)d_in[0];
  const float* dinp = (const float*)d_in[1];
  const float* We1  = (const float*)d_in[2];
  const float* be1  = (const float*)d_in[3];
  const float* We2  = (const float*)d_in[4];
  const float* be2  = (const float*)d_in[5];
  const float* We3  = (const float*)d_in[6];
  const float* be3  = (const float*)d_in[7];
  const float* Wd1  = (const float*)d_in[8];
  const float* bd1  = (const float*)d_in[9];
  const float* Wd2  = (const float*)d_in[10];
  const float* bd2  = (const float*)d_in[11];
  const float* Wd3  = (const float*)d_in[12];
  const float* bd3  = (const float*)d_in[13];

  float* y_out = (float*)d_out;
  float* z_out = y_out + (size_t)NROWS * DDIM;
  float* r_out = z_out + (size_t)NROWS * ZDIM;

  char* ws = (char*)d_ws;
  unsigned short* W1h = (unsigned short*)(ws + OFF_W1H);
  unsigned short* W1l = (unsigned short*)(ws + OFF_W1L);
  unsigned short* W2h = (unsigned short*)(ws + OFF_W2H);
  unsigned short* W2l = (unsigned short*)(ws + OFF_W2L);
  unsigned short* W5h = (unsigned short*)(ws + OFF_W5H);
  unsigned short* W5l = (unsigned short*)(ws + OFF_W5L);
  unsigned short* W6h = (unsigned short*)(ws + OFF_W6H);
  unsigned short* W6l = (unsigned short*)(ws + OFF_W6L);
  float* Cf    = (float*)(ws + OFF_C);
  float* msep  = (float*)(ws + OFF_MSEP);
  float* defen = (float*)(ws + OFF_DEFEN);
  float* cand  = (float*)(ws + OFF_CAND);

  (void)hipFuncSetAttribute((const void*)k_main, hipFuncAttributeMaxDynamicSharedMemorySize, LDS_TOTAL);

  k_prep<<<dim3(256), dim3(256), 0, stream>>>(We1, We2, Wd2, Wd3, dinp,
                                              W1h, W1l, W2h, W2l, W5h, W5l, W6h, W6l, Cf);
  k_main<<<dim3(2048), dim3(512), LDS_TOTAL, stream>>>(x, dinp, be1, be2, be3, bd1, bd2, bd3,
                                                       We3, Wd1, W1h, W1l, W2h, W2l, W5h, W5l,
                                                       W6h, W6l, Cf, y_out, z_out, defen, msep);
  k_topk_a<<<dim3(64), dim3(256), 0, stream>>>(defen, cand);
  k_topk_b<<<dim3(1), dim3(256), 0, stream>>>(cand, msep, r_out);
}

// Round 3
// 1538.925 us; speedup vs baseline: 1.2170x; 1.2170x over previous
//
#include <hip/hip_runtime.h>
#include <hip/hip_bf16.h>
#include <math.h>

typedef short bf16x8 __attribute__((ext_vector_type(8)));
typedef float f32x4 __attribute__((ext_vector_type(4)));
typedef unsigned int u32;

#define NROWS 131072
#define DDIM 224
#define HREAL 400
#define HP 416          // padded hidden dim (13*32)
#define ROWS 32         // rows per block
#define ASTRIDE 1664    // HP * 4 bytes (u32 per element: lo<<16|hi)

// ---- workspace layout (bytes) ----
#define OFF_W1H   0          // bf16 [416*224] fragment-linear
#define OFF_W1L   186368
#define OFF_W2H   372736     // bf16 [416*416]
#define OFF_W2L   718848
#define OFF_W5H   1064960
#define OFF_W5L   1411072
#define OFF_W6H   1757184    // bf16 [224*416]
#define OFF_W6L   1943552
#define OFF_C     2129920    // f32 scalar ||d||
#define OFF_MSEP  2129936    // f32 [4096]
#define OFF_DEFEN 2146320    // f32 [131072]
#define OFF_CAND  2670608    // f32 [1280]
// total 2675728 bytes

#define LDS_ACT   0                 // [32][416] u32 (lo<<16|hi), xor-swizzled
#define LDS_AUX   53248             // union: zbuf [32][4] f32 | red [32][2][4] f32
#define LDS_TOTAL 54272

__device__ __forceinline__ unsigned short f2bf(float v) {
  union { float f; u32 u; } a; a.f = v;
  u32 u = a.u;
  u += 0x7fffu + ((u >> 16) & 1u);   // round-to-nearest-even
  return (unsigned short)(u >> 16);
}
__device__ __forceinline__ float bf2f(unsigned short h) {
  union { u32 u; float f; } a; a.u = ((u32)h) << 16; return a.f;
}
__device__ __forceinline__ u32 packsplit(float v) {
  unsigned short hi = f2bf(v);
  unsigned short lo = f2bf(v - bf2f(hi));
  return ((u32)lo << 16) | (u32)hi;
}

// fragment-linear weight packing: element i -> (nb, ks, g, l15, e)
// lane l15 of group g reads 16B at ((nb*NKS+ks)*4+g)*256 + l15*16  (fully coalesced)
__device__ __forceinline__ void pack_w(int i, int KP, int KREAL, int NREAL, int NLD,
                                       const float* __restrict__ W,
                                       unsigned short* __restrict__ Wh,
                                       unsigned short* __restrict__ Wl) {
  const int e = i & 7, l15 = (i >> 3) & 15, g = (i >> 7) & 3;
  const int rest = i >> 9;
  const int nks = KP >> 5;
  const int ks = rest % nks, nb = rest / nks;
  const int n = nb * 16 + l15, k = ks * 32 + g * 8 + e;
  const float w = (n < NREAL && k < KREAL) ? W[k * NLD + n] : 0.f;
  const unsigned short h = f2bf(w);
  Wh[i] = h; Wl[i] = f2bf(w - bf2f(h));
}

// ---------------- prep: pack+split weights, ||d|| ----------------
__global__ void k_prep(const float* __restrict__ We1, const float* __restrict__ We2,
                       const float* __restrict__ Wd2, const float* __restrict__ Wd3,
                       const float* __restrict__ dvec,
                       unsigned short* __restrict__ W1h, unsigned short* __restrict__ W1l,
                       unsigned short* __restrict__ W2h, unsigned short* __restrict__ W2l,
                       unsigned short* __restrict__ W5h, unsigned short* __restrict__ W5l,
                       unsigned short* __restrict__ W6h, unsigned short* __restrict__ W6l,
                       float* __restrict__ Cout) {
  const int t = blockIdx.x * 256 + threadIdx.x;
  const int NT = gridDim.x * 256;
  for (int i = t; i < HP * DDIM; i += NT) pack_w(i, DDIM, DDIM, HREAL, HREAL, We1, W1h, W1l);
  for (int i = t; i < HP * HP;   i += NT) pack_w(i, HP, HREAL, HREAL, HREAL, We2, W2h, W2l);
  for (int i = t; i < HP * HP;   i += NT) pack_w(i, HP, HREAL, HREAL, HREAL, Wd2, W5h, W5l);
  for (int i = t; i < DDIM * HP; i += NT) pack_w(i, HP, HREAL, DDIM, DDIM, Wd3, W6h, W6l);
  if (blockIdx.x == 0) {
    float s = 0.f;
    for (int i = threadIdx.x; i < DDIM; i += 256) { float v = dvec[i]; s += v * v; }
#pragma unroll
    for (int off = 1; off < 64; off <<= 1) s += __shfl_xor(s, off);
    __shared__ float cs[4];
    if ((threadIdx.x & 63) == 0) cs[threadIdx.x >> 6] = s;
    __syncthreads();
    if (threadIdx.x == 0) Cout[0] = sqrtf(cs[0] + cs[1] + cs[2] + cs[3]);
  }
}

union U8 { bf16x8 v; u32 w[4]; };

__device__ __forceinline__ void unpack8(uint4 p, uint4 q, bf16x8& hi, bf16x8& lo) {
  U8 h, l;
  h.w[0] = (p.x & 0xffffu) | (p.y << 16);
  h.w[1] = (p.z & 0xffffu) | (p.w << 16);
  h.w[2] = (q.x & 0xffffu) | (q.y << 16);
  h.w[3] = (q.z & 0xffffu) | (q.w << 16);
  l.w[0] = (p.x >> 16) | (p.y & 0xffff0000u);
  l.w[1] = (p.z >> 16) | (p.w & 0xffff0000u);
  l.w[2] = (q.x >> 16) | (q.y & 0xffff0000u);
  l.w[3] = (q.z >> 16) | (q.w & 0xffff0000u);
  hi = h.v; lo = l.v;
}

// ---------------- fused MLP layer: act(LDS) @ Wt + b -> lrelu -> act(LDS) -------
// 4 waves = 2 M-waves (16 rows) x 2 N-waves (NFRAG*16 cols)
template <int KP, int NFRAG>
__device__ __forceinline__ void mfma_layer(char* actb,
                                           const unsigned short* __restrict__ Wh,
                                           const unsigned short* __restrict__ Wl,
                                           const float* __restrict__ bias, int realN,
                                           int m0, int nwave, int l15, int g) {
  constexpr int NKS = KP / 32;
  f32x4 acc[NFRAG] = {};
  const int arow = m0 + l15;
  const char* abase = actb + arow * ASTRIDE;
  const int swz = (arow & 7) << 4;
  const int lof = g * 128 + l15 * 8;
#pragma unroll 1
  for (int ks = 0; ks < NKS; ++ks) {
    const int b0 = ks * 128 + g * 32;
    uint4 p = *(const uint4*)(abase + (b0 ^ swz));
    uint4 q = *(const uint4*)(abase + ((b0 + 16) ^ swz));
    bf16x8 ah, al;
    unpack8(p, q, ah, al);
#pragma unroll
    for (int nf = 0; nf < NFRAG; ++nf) {
      const int nb = nwave * NFRAG + nf;
      const size_t off = (size_t)(((nb * NKS + ks) << 9) + lof);
      const bf16x8 bh = *(const bf16x8*)(Wh + off);
      const bf16x8 bl = *(const bf16x8*)(Wl + off);
      acc[nf] = __builtin_amdgcn_mfma_f32_16x16x32_bf16(ah, bh, acc[nf], 0, 0, 0);
      acc[nf] = __builtin_amdgcn_mfma_f32_16x16x32_bf16(al, bh, acc[nf], 0, 0, 0);
      acc[nf] = __builtin_amdgcn_mfma_f32_16x16x32_bf16(ah, bl, acc[nf], 0, 0, 0);
    }
  }
  __syncthreads();   // everyone done reading act
#pragma unroll
  for (int nf = 0; nf < NFRAG; ++nf) {
    const int col = nwave * (NFRAG * 16) + nf * 16 + l15;
    const float bv = (col < realN) ? bias[col] : 0.0f;
#pragma unroll
    for (int j = 0; j < 4; ++j) {
      const int row = m0 + g * 4 + j;
      float v = acc[nf][j] + bv;
      v = fmaxf(v, 0.1f * v);   // leaky relu
      *(u32*)(actb + row * ASTRIDE + ((col * 4) ^ ((row & 7) << 4))) = packsplit(v);
    }
  }
  __syncthreads();
}

// ---------------- main fused kernel: 32 rows per block, 256 threads ----------------
__global__ __launch_bounds__(256, 3) void k_main(
    const float* __restrict__ xin, const float* __restrict__ dvec,
    const float* __restrict__ be1, const float* __restrict__ be2, const float* __restrict__ be3,
    const float* __restrict__ bd1, const float* __restrict__ bd2, const float* __restrict__ bd3,
    const float* __restrict__ We3, const float* __restrict__ Wd1,
    const unsigned short* __restrict__ W1h, const unsigned short* __restrict__ W1l,
    const unsigned short* __restrict__ W2h, const unsigned short* __restrict__ W2l,
    const unsigned short* __restrict__ W5h, const unsigned short* __restrict__ W5l,
    const unsigned short* __restrict__ W6h, const unsigned short* __restrict__ W6l,
    const float* __restrict__ Cptr,
    float* __restrict__ y_out, float* __restrict__ z_out,
    float* __restrict__ defen, float* __restrict__ msep) {
  extern __shared__ __align__(16) char lds[];
  char* actb = lds + LDS_ACT;
  float* zbuf = (float*)(lds + LDS_AUX);   // [32][4]
  float* red  = (float*)(lds + LDS_AUX);   // [32][2][4] (disjoint lifetime vs zbuf)

  const int tid = threadIdx.x;
  const int lane = tid & 63;
  const int wid = tid >> 6;       // 0..3
  const int m0 = (wid >> 1) * 16; // 2 M-waves
  const int nwave = wid & 1;      // 2 N-waves
  const int l15 = lane & 15;
  const int g = lane >> 4;        // 0..3
  const int row0 = blockIdx.x * ROWS;

  // ---- stage x -> act (split bf16 pair, swizzled), vectorized float4 ----
#pragma unroll
  for (int i = 0; i < 7; ++i) {
    int f = i * 256 + tid;                       // 0 .. 1791 (32 rows * 56 float4)
    int r = f / 56, c4 = f - r * 56;
    float4 v = *(const float4*)(xin + (size_t)(row0 + r) * DDIM + c4 * 4);
    uint4 pk;
    pk.x = packsplit(v.x); pk.y = packsplit(v.y);
    pk.z = packsplit(v.z); pk.w = packsplit(v.w);
    *(uint4*)(actb + r * ASTRIDE + ((c4 * 16) ^ ((r & 7) << 4))) = pk;
  }
  __syncthreads();

  // ---- L1: x(224) -> h1(400), L2: h1 -> h2(400) ----
  mfma_layer<DDIM, 13>(actb, W1h, W1l, be1, HREAL, m0, nwave, l15, g);
  mfma_layer<HP, 13>(actb, W2h, W2l, be2, HREAL, m0, nwave, l15, g);

  // ---- L3: z = h2 @ We3 + be3 (Z=4), f32, all 256 threads ----
  {
    const int r = tid >> 3, t8 = tid & 7;
    const int j = t8 & 3, half = t8 >> 2;
    const char* abase = actb + r * ASTRIDE;
    const int swz = (r & 7) << 4;
    float s = 0.f;
#pragma unroll 1
    for (int it = 0; it < 25; ++it) {
      const int k = half * 200 + it * 8;
      uint4 p = *(const uint4*)(abase + ((k * 4) ^ swz));
      uint4 q = *(const uint4*)(abase + ((k * 4 + 16) ^ swz));
      u32 e[8] = {p.x, p.y, p.z, p.w, q.x, q.y, q.z, q.w};
#pragma unroll
      for (int u = 0; u < 8; ++u) {
        float h = bf2f((unsigned short)(e[u] & 0xffffu)) + bf2f((unsigned short)(e[u] >> 16));
        s = fmaf(h, We3[(k + u) * 4 + j], s);
      }
    }
    s += __shfl_xor(s, 4);
    if (half == 0) {
      s += be3[j];
      z_out[(size_t)(row0 + r) * 4 + j] = s;
      zbuf[r * 4 + j] = s;
    }
  }
  __syncthreads();

  // ---- L4: g1 = lrelu(z @ Wd1 + bd1) -> act, f32, vectorized ----
  {
    const int r = tid >> 3, q = tid & 7;
    const float z0 = zbuf[r * 4 + 0], z1 = zbuf[r * 4 + 1];
    const float z2 = zbuf[r * 4 + 2], z3 = zbuf[r * 4 + 3];
    char* abase = actb + r * ASTRIDE;
    const int swz = (r & 7) << 4;
#pragma unroll 1
    for (int u = 0; u < 13; ++u) {
      const int c4 = q * 13 + u;
      uint4 pk;
      u32* pw = (u32*)&pk;
#pragma unroll
      for (int w = 0; w < 4; ++w) {
        const int c = c4 * 4 + w;
        float v = 0.f;
        if (c < HREAL) {
          v = fmaf(z0, Wd1[c], fmaf(z1, Wd1[HREAL + c], fmaf(z2, Wd1[2 * HREAL + c], fmaf(z3, Wd1[3 * HREAL + c], bd1[c]))));
          v = fmaxf(v, 0.1f * v);
        }
        pw[w] = packsplit(v);
      }
      *(uint4*)(abase + ((c4 * 16) ^ swz)) = pk;
    }
  }
  __syncthreads();

  // ---- L5: g2 = lrelu(g1 @ Wd2 + bd2) ----
  mfma_layer<HP, 13>(actb, W5h, W5l, bd2, HREAL, m0, nwave, l15, g);

  // ---- L6: y = tanh(g2 @ Wd3 + bd3) + fused reductions ----
  {
    f32x4 acc[7] = {};
    const int arow = m0 + l15;
    const char* abase = actb + arow * ASTRIDE;
    const int swz = (arow & 7) << 4;
    const int lof = g * 128 + l15 * 8;
#pragma unroll 1
    for (int ks = 0; ks < HP / 32; ++ks) {
      const int b0 = ks * 128 + g * 32;
      uint4 p = *(const uint4*)(abase + (b0 ^ swz));
      uint4 q = *(const uint4*)(abase + ((b0 + 16) ^ swz));
      bf16x8 ah, al;
      unpack8(p, q, ah, al);
#pragma unroll
      for (int nf = 0; nf < 7; ++nf) {
        const int nb = nwave * 7 + nf;
        const size_t off = (size_t)(((nb * 13 + ks) << 9) + lof);
        const bf16x8 bh = *(const bf16x8*)(W6h + off);
        const bf16x8 bl = *(const bf16x8*)(W6l + off);
        acc[nf] = __builtin_amdgcn_mfma_f32_16x16x32_bf16(ah, bh, acc[nf], 0, 0, 0);
        acc[nf] = __builtin_amdgcn_mfma_f32_16x16x32_bf16(al, bh, acc[nf], 0, 0, 0);
        acc[nf] = __builtin_amdgcn_mfma_f32_16x16x32_bf16(ah, bl, acc[nf], 0, 0, 0);
      }
    }
#pragma unroll
    for (int j = 0; j < 4; ++j) {
      const int lrow = m0 + g * 4 + j;
      const int grow = row0 + lrow;
      float pA = 0.f, pB = 0.f, pM = 0.f;
#pragma unroll
      for (int nf = 0; nf < 7; ++nf) {
        const int col = nwave * 112 + nf * 16 + l15;
        float v = acc[nf][j] + bd3[col];
        float y = tanhf(v);
        y_out[(size_t)grow * DDIM + col] = y;
        float dv = dvec[col];
        float xv = xin[(size_t)grow * DDIM + col];
        pA = fmaf(y, dv, pA);
        pB = fmaf(y, y, pB);
        float df = y - xv;
        pM = fmaf(df, df, pM);
      }
#pragma unroll
      for (int off = 1; off < 16; off <<= 1) {
        pA += __shfl_xor(pA, off);
        pB += __shfl_xor(pB, off);
        pM += __shfl_xor(pM, off);
      }
      if (l15 == 0) {
        float* rr = &red[(lrow * 2 + nwave) * 4];
        rr[0] = pA; rr[1] = pB; rr[2] = pM;
      }
    }
  }
  __syncthreads();

  if (tid < 32) {
    const float Cn = Cptr[0];
    const int r = tid;
    float A  = red[(r * 2 + 0) * 4 + 0] + red[(r * 2 + 1) * 4 + 0];
    float B2 = red[(r * 2 + 0) * 4 + 1] + red[(r * 2 + 1) * 4 + 1];
    float Mloc = red[(r * 2 + 0) * 4 + 2] + red[(r * 2 + 1) * 4 + 2];
    defen[row0 + r] = A / (sqrtf(B2) * Cn + 1e-5f);
#pragma unroll
    for (int off = 1; off < 32; off <<= 1) Mloc += __shfl_xor(Mloc, off);
    if (tid == 0) msep[blockIdx.x] = Mloc;
  }
}

// ---------------- top-k stage A: 64 blocks, per-block top-20 of 2048 ----------------
__global__ void k_topk_a(const float* __restrict__ defen, float* __restrict__ cand) {
  __shared__ float vals[2048];
  __shared__ float wv[4];
  __shared__ int wi[4];
  const int tid = threadIdx.x;
  const int base = blockIdx.x * 2048;
  for (int i = tid; i < 2048; i += 256) vals[i] = defen[base + i];
  __syncthreads();
  for (int it = 0; it < 20; ++it) {
    float mv = -1e30f; int mi = 1 << 30;
    for (int i = tid; i < 2048; i += 256) {
      float v = vals[i];
      if (v > mv) { mv = v; mi = i; }
    }
#pragma unroll
    for (int off = 1; off < 64; off <<= 1) {
      float ov = __shfl_xor(mv, off); int oi = __shfl_xor(mi, off);
      if (ov > mv || (ov == mv && oi < mi)) { mv = ov; mi = oi; }
    }
    if ((tid & 63) == 0) { wv[tid >> 6] = mv; wi[tid >> 6] = mi; }
    __syncthreads();
    if (tid == 0) {
      float bv = wv[0]; int bi = wi[0];
      for (int q = 1; q < 4; ++q)
        if (wv[q] > bv || (wv[q] == bv && wi[q] < bi)) { bv = wv[q]; bi = wi[q]; }
      cand[blockIdx.x * 20 + it] = bv;
      vals[bi] = -1e30f;
    }
    __syncthreads();
  }
}

// ---------------- top-k stage B: final top-20 of 1280 + R_loss ----------------
__global__ void k_topk_b(const float* __restrict__ cand, const float* __restrict__ msep,
                         float* __restrict__ rloss) {
  __shared__ float vals[1280];
  __shared__ float wv[4];
  __shared__ int wi[4];
  __shared__ float msum[4];
  const int tid = threadIdx.x;
  for (int i = tid; i < 1280; i += 256) vals[i] = cand[i];
  float ms = 0.f;
  for (int i = tid; i < 4096; i += 256) ms += msep[i];
#pragma unroll
  for (int off = 1; off < 64; off <<= 1) ms += __shfl_xor(ms, off);
  if ((tid & 63) == 0) msum[tid >> 6] = ms;
  __syncthreads();
  float sam = 0.f;
  for (int it = 0; it < 20; ++it) {
    float mv = -1e30f; int mi = 1 << 30;
    for (int i = tid; i < 1280; i += 256) {
      float v = vals[i];
      if (v > mv) { mv = v; mi = i; }
    }
#pragma unroll
    for (int off = 1; off < 64; off <<= 1) {
      float ov = __shfl_xor(mv, off); int oi = __shfl_xor(mi, off);
      if (ov > mv || (ov == mv && oi < mi)) { mv = ov; mi = oi; }
    }
    if ((tid & 63) == 0) { wv[tid >> 6] = mv; wi[tid >> 6] = mi; }
    __syncthreads();
    if (tid == 0) {
      float bv = wv[0]; int bi = wi[0];
      for (int q = 1; q < 4; ++q)
        if (wv[q] > bv || (wv[q] == bv && wi[q] < bi)) { bv = wv[q]; bi = wi[q]; }
      sam += bv;
      vals[bi] = -1e30f;
    }
    __syncthreads();
  }
  if (tid == 0) {
    float mse = (msum[0] + msum[1] + msum[2] + msum[3]) / 29360128.f;  // N*D
    rloss[0] = mse + 0.1f * sam;
  }
}

extern "C" void kernel_launch(void* const* d_in, const int* in_sizes, int n_in,
                              void* d_out, int out_size, void* d_ws, size_t ws_size,
                              hipStream_t stream) {
  const float* x    = (const float*)d_in[0];
  const float* dinp = (const float*)d_in[1];
  const float* We1  = (const float*)d_in[2];
  const float* be1  = (const float*)d_in[3];
  const float* We2  = (const float*)d_in[4];
  const float* be2  = (const float*)d_in[5];
  const float* We3  = (const float*)d_in[6];
  const float* be3  = (const float*)d_in[7];
  const float* Wd1  = (const float*)d_in[8];
  const float* bd1  = (const float*)d_in[9];
  const float* Wd2  = (const float*)d_in[10];
  const float* bd2  = (const float*)d_in[11];
  const float* Wd3  = (const float*)d_in[12];
  const float* bd3  = (const float*)d_in[13];

  float* y_out = (float*)d_out;
  float* z_out = y_out + (size_t)NROWS * DDIM;
  float* r_out = z_out + (size_t)NROWS * 4;

  char* ws = (char*)d_ws;
  unsigned short* W1h = (unsigned short*)(ws + OFF_W1H);
  unsigned short* W1l = (unsigned short*)(ws + OFF_W1L);
  unsigned short* W2h = (unsigned short*)(ws + OFF_W2H);
  unsigned short* W2l = (unsigned short*)(ws + OFF_W2L);
  unsigned short* W5h = (unsigned short*)(ws + OFF_W5H);
  unsigned short* W5l = (unsigned short*)(ws + OFF_W5L);
  unsigned short* W6h = (unsigned short*)(ws + OFF_W6H);
  unsigned short* W6l = (unsigned short*)(ws + OFF_W6L);
  float* Cf    = (float*)(ws + OFF_C);
  float* msep  = (float*)(ws + OFF_MSEP);
  float* defen = (float*)(ws + OFF_DEFEN);
  float* cand  = (float*)(ws + OFF_CAND);

  (void)hipFuncSetAttribute((const void*)k_main, hipFuncAttributeMaxDynamicSharedMemorySize, LDS_TOTAL);

  k_prep<<<dim3(256), dim3(256), 0, stream>>>(We1, We2, Wd2, Wd3, dinp,
                                              W1h, W1l, W2h, W2l, W5h, W5l, W6h, W6l, Cf);
  k_main<<<dim3(4096), dim3(256), LDS_TOTAL, stream>>>(x, dinp, be1, be2, be3, bd1, bd2, bd3,
                                                       We3, Wd1, W1h, W1l, W2h, W2l, W5h, W5l,
                                                       W6h, W6l, Cf, y_out, z_out, defen, msep);
  k_topk_a<<<dim3(64), dim3(256), 0, stream>>>(defen, cand);
  k_topk_b<<<dim3(1), dim3(256), 0, stream>>>(cand, msep, r_out);
}

// Round 6
// 898.771 us; speedup vs baseline: 2.0838x; 1.7123x over previous
//
#include <hip/hip_runtime.h>
#include <hip/hip_bf16.h>
#include <math.h>

typedef short bf16x8 __attribute__((ext_vector_type(8)));
typedef float f32x4 __attribute__((ext_vector_type(4)));
typedef unsigned int u32;
typedef unsigned short u16;

#define NROWS 131072
#define DDIM 224
#define HREAL 400
#define HP 416          // padded hidden dim (13*32)
#define ROWS 32         // rows per block
#define PROW 832        // bytes per plane row (416 * 2B = 52 units of 16B)
#define PLANE 26624     // 32 * 832
#define LDS_TOTAL 53248 // two planes; 3 blocks/CU (3*53248 = 159744 <= 163840)

// ---- workspace layout (bytes) ----
#define OFF_W1H   0          // bf16 [416*224] fragment-linear
#define OFF_W1L   186368
#define OFF_W2H   372736     // bf16 [416*416]
#define OFF_W2L   718848
#define OFF_W5H   1064960
#define OFF_W5L   1411072
#define OFF_W6H   1757184    // bf16 [224*416]
#define OFF_W6L   1943552
#define OFF_C     2129920    // f32 scalar ||d||
#define OFF_MSEP  2129936    // f32 [4096]
#define OFF_DEFEN 2146320    // f32 [131072]
#define OFF_CAND  2670608    // f32 [1280]
// total 2675728 bytes

__device__ __forceinline__ u16 f2bf(float v) {
  union { float f; u32 u; } a; a.f = v;
  u32 u = a.u;
  u += 0x7fffu + ((u >> 16) & 1u);   // round-to-nearest-even
  return (u16)(u >> 16);
}
__device__ __forceinline__ float bf2f(u16 h) {
  union { u32 u; float f; } a; a.u = ((u32)h) << 16; return a.f;
}
// rotation swizzle: 16B unit u of row r lives at unit (u+r) mod 52.
// bijective within the row for ANY row stride; 8 consecutive rows map to 8
// distinct bank groups (208 dwords stride -> (5r+u) mod 8), so stride-PROW
// b128 column reads are ~2-way (free) instead of 8-way.
__device__ __forceinline__ int rotu(int r, int u) {
  int s = u + r; return (s >= 52) ? s - 52 : s;
}

// fragment-linear weight packing: element i -> (nb, ks, g, l15, e)
__device__ __forceinline__ void pack_w(int i, int KP, int KREAL, int NREAL, int NLD,
                                       const float* __restrict__ W,
                                       u16* __restrict__ Wh, u16* __restrict__ Wl) {
  const int e = i & 7, l15 = (i >> 3) & 15, g = (i >> 7) & 3;
  const int rest = i >> 9;
  const int nks = KP >> 5;
  const int ks = rest % nks, nb = rest / nks;
  const int n = nb * 16 + l15, k = ks * 32 + g * 8 + e;
  const float w = (n < NREAL && k < KREAL) ? W[k * NLD + n] : 0.f;
  const u16 h = f2bf(w);
  Wh[i] = h; Wl[i] = f2bf(w - bf2f(h));
}

__global__ void k_prep(const float* __restrict__ We1, const float* __restrict__ We2,
                       const float* __restrict__ Wd2, const float* __restrict__ Wd3,
                       const float* __restrict__ dvec,
                       u16* __restrict__ W1h, u16* __restrict__ W1l,
                       u16* __restrict__ W2h, u16* __restrict__ W2l,
                       u16* __restrict__ W5h, u16* __restrict__ W5l,
                       u16* __restrict__ W6h, u16* __restrict__ W6l,
                       float* __restrict__ Cout) {
  const int t = blockIdx.x * 256 + threadIdx.x;
  const int NT = gridDim.x * 256;
  for (int i = t; i < HP * DDIM; i += NT) pack_w(i, DDIM, DDIM, HREAL, HREAL, We1, W1h, W1l);
  for (int i = t; i < HP * HP;   i += NT) pack_w(i, HP, HREAL, HREAL, HREAL, We2, W2h, W2l);
  for (int i = t; i < HP * HP;   i += NT) pack_w(i, HP, HREAL, HREAL, HREAL, Wd2, W5h, W5l);
  for (int i = t; i < DDIM * HP; i += NT) pack_w(i, HP, HREAL, DDIM, DDIM, Wd3, W6h, W6l);
  if (blockIdx.x == 0) {
    float s = 0.f;
    for (int i = threadIdx.x; i < DDIM; i += 256) { float v = dvec[i]; s += v * v; }
#pragma unroll
    for (int off = 1; off < 64; off <<= 1) s += __shfl_xor(s, off);
    __shared__ float cs[4];
    if ((threadIdx.x & 63) == 0) cs[threadIdx.x >> 6] = s;
    __syncthreads();
    if (threadIdx.x == 0) Cout[0] = sqrtf(cs[0] + cs[1] + cs[2] + cs[3]);
  }
}

// ---------------- GEMM core: one wave, 2 M-frags x NFW N-frags ----------------
// acc layout: acc[mf*7 + nf], mf in {0,1}
template <int NKS, int NFW>
__device__ __forceinline__ void gemm_acc(const char* hp, const char* lp,
    const u16* __restrict__ Wh, const u16* __restrict__ Wl,
    int nb0, int l15, int g, f32x4 (&acc)[14]) {
  const char* h0 = hp + l15 * PROW;
  const char* l0 = lp + l15 * PROW;
  const char* h1 = hp + (l15 + 16) * PROW;
  const char* l1 = lp + (l15 + 16) * PROW;
  const int lof = (g << 7) + (l15 << 3);
  const int ub = g + l15;          // unit base for row l15 (u = ks*4 + g, rot += l15)
#pragma unroll 2
  for (int ks = 0; ks < NKS; ++ks) {
    int u0 = ks * 4 + ub; if (u0 >= 52) u0 -= 52;   // ks*4+g <= 51, +l15 <= 66
    int u1 = u0 + 16;     if (u1 >= 52) u1 -= 52;   // rot for row l15+16
    const bf16x8 ah0 = *(const bf16x8*)(h0 + u0 * 16);
    const bf16x8 al0 = *(const bf16x8*)(l0 + u0 * 16);
    const bf16x8 ah1 = *(const bf16x8*)(h1 + u1 * 16);
    const bf16x8 al1 = *(const bf16x8*)(l1 + u1 * 16);
#pragma unroll
    for (int nf = 0; nf < NFW; ++nf) {
      const int off = (((nb0 + nf) * NKS + ks) << 9) + lof;
      const bf16x8 bh = *(const bf16x8*)(Wh + off);
      const bf16x8 bl = *(const bf16x8*)(Wl + off);
      acc[nf]     = __builtin_amdgcn_mfma_f32_16x16x32_bf16(ah0, bh, acc[nf], 0, 0, 0);
      acc[nf]     = __builtin_amdgcn_mfma_f32_16x16x32_bf16(al0, bh, acc[nf], 0, 0, 0);
      acc[nf]     = __builtin_amdgcn_mfma_f32_16x16x32_bf16(ah0, bl, acc[nf], 0, 0, 0);
      acc[7 + nf] = __builtin_amdgcn_mfma_f32_16x16x32_bf16(ah1, bh, acc[7 + nf], 0, 0, 0);
      acc[7 + nf] = __builtin_amdgcn_mfma_f32_16x16x32_bf16(al1, bh, acc[7 + nf], 0, 0, 0);
      acc[7 + nf] = __builtin_amdgcn_mfma_f32_16x16x32_bf16(ah1, bl, acc[7 + nf], 0, 0, 0);
    }
  }
}

// ---------------- activation epilogue: bias + lrelu -> hi/lo planes ----------------
template <int NFW>
__device__ __forceinline__ void epi_act(f32x4 (&acc)[14], const float* __restrict__ bias,
                                        int nb0, char* hp, char* lp, int l15, int g) {
#pragma unroll
  for (int nf = 0; nf < NFW; ++nf) {
    const int col = (nb0 + nf) * 16 + l15;
    const float bv = (col < HREAL) ? bias[col] : 0.f;
    const int cu = col >> 3;            // 16B unit index
    const int crem = (col & 7) * 2;     // byte within unit
#pragma unroll
    for (int mf = 0; mf < 2; ++mf) {
#pragma unroll
      for (int j = 0; j < 4; ++j) {
        const int row = mf * 16 + g * 4 + j;
        float v = acc[mf * 7 + nf][j] + bv;
        v = fmaxf(v, 0.1f * v);
        const u16 h = f2bf(v);
        const u16 lo = f2bf(v - bf2f(h));
        const int boff = row * PROW + rotu(row, cu) * 16 + crem;
        *(u16*)(hp + boff) = h;
        *(u16*)(lp + boff) = lo;
      }
    }
  }
}

// ---------------- main fused kernel: 32 rows per block, 256 threads ----------------
__global__ __launch_bounds__(256, 3) void k_main(
    const float* __restrict__ xin, const float* __restrict__ dvec,
    const float* __restrict__ be1, const float* __restrict__ be2, const float* __restrict__ be3,
    const float* __restrict__ bd1, const float* __restrict__ bd2, const float* __restrict__ bd3,
    const float* __restrict__ We3, const float* __restrict__ Wd1,
    const u16* __restrict__ W1h, const u16* __restrict__ W1l,
    const u16* __restrict__ W2h, const u16* __restrict__ W2l,
    const u16* __restrict__ W5h, const u16* __restrict__ W5l,
    const u16* __restrict__ W6h, const u16* __restrict__ W6l,
    const float* __restrict__ Cptr,
    float* __restrict__ y_out, float* __restrict__ z_out,
    float* __restrict__ defen, float* __restrict__ msep) {
  extern __shared__ __align__(16) char lds[];
  char* hp = lds;              // [32][416] bf16 hi plane, rotation-swizzled
  char* lp = lds + PLANE;      // [32][416] bf16 lo plane

  const int tid = threadIdx.x;
  const int lane = tid & 63;
  const int wid = tid >> 6;       // 0..3
  const int l15 = lane & 15;
  const int g = lane >> 4;        // 0..3
  const int row0 = blockIdx.x * ROWS;
  // N-chunk split over 4 waves for hidden layers: 26 blocks -> {7,7,6,6}
  const int nb0_26 = (wid < 2) ? wid * 7 : 14 + (wid - 2) * 6;

  // ---- stage x -> planes ----
#pragma unroll
  for (int i = 0; i < 7; ++i) {
    const int f = i * 256 + tid;                 // 32 rows * 56 float4
    const int r = f / 56, c4 = f - r * 56;       // c4: 8-byte group (4 cols)
    const float4 v = *(const float4*)(xin + (size_t)(row0 + r) * DDIM + c4 * 4);
    const float vv[4] = {v.x, v.y, v.z, v.w};
    ushort4 hh, ll;
    u16* hw = (u16*)&hh; u16* lw = (u16*)&ll;
#pragma unroll
    for (int w = 0; w < 4; ++w) {
      const u16 h = f2bf(vv[w]);
      hw[w] = h; lw[w] = f2bf(vv[w] - bf2f(h));
    }
    const int boff = r * PROW + rotu(r, c4 >> 1) * 16 + (c4 & 1) * 8;
    *(ushort4*)(hp + boff) = hh;
    *(ushort4*)(lp + boff) = ll;
  }
  __syncthreads();

  // ---- L1: x(224) -> h1 ----
  {
    f32x4 acc[14] = {};
    if (wid < 2) gemm_acc<7, 7>(hp, lp, W1h, W1l, nb0_26, l15, g, acc);
    else         gemm_acc<7, 6>(hp, lp, W1h, W1l, nb0_26, l15, g, acc);
    __syncthreads();
    if (wid < 2) epi_act<7>(acc, be1, nb0_26, hp, lp, l15, g);
    else         epi_act<6>(acc, be1, nb0_26, hp, lp, l15, g);
  }
  __syncthreads();

  // ---- L2: h1 -> h2 ----
  {
    f32x4 acc[14] = {};
    if (wid < 2) gemm_acc<13, 7>(hp, lp, W2h, W2l, nb0_26, l15, g, acc);
    else         gemm_acc<13, 6>(hp, lp, W2h, W2l, nb0_26, l15, g, acc);
    __syncthreads();
    if (wid < 2) epi_act<7>(acc, be2, nb0_26, hp, lp, l15, g);
    else         epi_act<6>(acc, be2, nb0_26, hp, lp, l15, g);
  }
  __syncthreads();

  // ---- L3: z = h2 @ We3 + be3 (Z=4), f32; z stays in registers ----
  float zval;   // z_{t8&3} for row tid>>3
  {
    const int r = tid >> 3, t8 = tid & 7;
    const int j = t8 & 3, half = t8 >> 2;
    const char* hb = hp + r * PROW;
    const char* lb = lp + r * PROW;
    float s0 = 0.f, s1 = 0.f;
#pragma unroll 2
    for (int it = 0; it < 25; ++it) {
      const int k = half * 200 + it * 8;
      const int uo = rotu(r, k >> 3) * 16;
      const bf16x8 h8 = *(const bf16x8*)(hb + uo);
      const bf16x8 l8 = *(const bf16x8*)(lb + uo);
#pragma unroll
      for (int u = 0; u < 8; ++u) {
        const float h = bf2f((u16)h8[u]) + bf2f((u16)l8[u]);
        if (u & 1) s1 = fmaf(h, We3[(k + u) * 4 + j], s1);
        else       s0 = fmaf(h, We3[(k + u) * 4 + j], s0);
      }
    }
    float s = s0 + s1;
    s += __shfl_xor(s, 4);
    s += be3[j];
    zval = s;
    if (half == 0) z_out[(size_t)(row0 + r) * 4 + j] = s;
  }
  // no barrier needed: each row is read (L3) and written (L4) only by its own
  // 8-thread group within one wave; program order serializes them.

  // ---- L4: g1 = lrelu(z @ Wd1 + bd1) -> planes ----
  {
    const int r = tid >> 3, q = tid & 7;
    float z[4];
#pragma unroll
    for (int j = 0; j < 4; ++j) z[j] = __shfl(zval, (lane & ~7) + j);
#pragma unroll 2
    for (int uu = 0; uu < 13; ++uu) {
      const int c4 = q * 13 + uu;                // 104 groups of 4 cols = 416
      ushort4 hh, ll;
      u16* hw = (u16*)&hh; u16* lw = (u16*)&ll;
#pragma unroll
      for (int w = 0; w < 4; ++w) {
        const int c = c4 * 4 + w;
        float v = 0.f;
        if (c < HREAL) {
          v = fmaf(z[0], Wd1[c], fmaf(z[1], Wd1[HREAL + c],
              fmaf(z[2], Wd1[2 * HREAL + c], fmaf(z[3], Wd1[3 * HREAL + c], bd1[c]))));
          v = fmaxf(v, 0.1f * v);
        }
        const u16 h = f2bf(v);
        hw[w] = h; lw[w] = f2bf(v - bf2f(h));
      }
      const int boff = r * PROW + rotu(r, c4 >> 1) * 16 + (c4 & 1) * 8;
      *(ushort4*)(hp + boff) = hh;
      *(ushort4*)(lp + boff) = ll;
    }
  }
  __syncthreads();

  // ---- L5: g2 = lrelu(g1 @ Wd2 + bd2) ----
  {
    f32x4 acc[14] = {};
    if (wid < 2) gemm_acc<13, 7>(hp, lp, W5h, W5l, nb0_26, l15, g, acc);
    else         gemm_acc<13, 6>(hp, lp, W5h, W5l, nb0_26, l15, g, acc);
    __syncthreads();
    if (wid < 2) epi_act<7>(acc, bd2, nb0_26, hp, lp, l15, g);
    else         epi_act<6>(acc, bd2, nb0_26, hp, lp, l15, g);
  }
  __syncthreads();

  // ---- L6: y = tanh(g2 @ Wd3 + bd3) + fused reductions ----
  // 14 n-blocks -> {4,4,3,3}
  {
    const int nb0 = (wid < 2) ? wid * 4 : 8 + (wid - 2) * 3;
    const int nfw = (wid < 2) ? 4 : 3;
    f32x4 acc[14] = {};
    if (wid < 2) gemm_acc<13, 4>(hp, lp, W6h, W6l, nb0, l15, g, acc);
    else         gemm_acc<13, 3>(hp, lp, W6h, W6l, nb0, l15, g, acc);
    __syncthreads();               // all act reads done; red overlays planes
    float* red = (float*)lds;      // [32][4][4]
#pragma unroll
    for (int mf = 0; mf < 2; ++mf) {
#pragma unroll
      for (int j = 0; j < 4; ++j) {
        const int lrow = mf * 16 + g * 4 + j;
        const int grow = row0 + lrow;
        float pA = 0.f, pB = 0.f, pM = 0.f;
#pragma unroll
        for (int nf = 0; nf < 4; ++nf) {
          if (nf < nfw) {
            const int col = (nb0 + nf) * 16 + l15;
            const float v = acc[mf * 7 + nf][j] + bd3[col];
            const float e = __expf(2.f * v);
            const float y = 1.f - 2.f * __builtin_amdgcn_rcpf(e + 1.f);
            y_out[(size_t)grow * DDIM + col] = y;
            pA = fmaf(y, dvec[col], pA);
            pB = fmaf(y, y, pB);
            const float df = y - xin[(size_t)grow * DDIM + col];
            pM = fmaf(df, df, pM);
          }
        }
#pragma unroll
        for (int off = 1; off < 16; off <<= 1) {
          pA += __shfl_xor(pA, off);
          pB += __shfl_xor(pB, off);
          pM += __shfl_xor(pM, off);
        }
        if (l15 == 0) {
          red[lrow * 16 + wid * 4 + 0] = pA;
          red[lrow * 16 + wid * 4 + 1] = pB;
          red[lrow * 16 + wid * 4 + 2] = pM;
        }
      }
    }
  }
  __syncthreads();

  if (tid < 32) {
    const float Cn = Cptr[0];
    const float* red = (const float*)lds;
    float A = 0.f, B2 = 0.f, M = 0.f;
#pragma unroll
    for (int w = 0; w < 4; ++w) {
      A  += red[tid * 16 + w * 4 + 0];
      B2 += red[tid * 16 + w * 4 + 1];
      M  += red[tid * 16 + w * 4 + 2];
    }
    defen[row0 + tid] = A / (sqrtf(B2) * Cn + 1e-5f);
#pragma unroll
    for (int off = 1; off < 32; off <<= 1) M += __shfl_xor(M, off);
    if (tid == 0) msep[blockIdx.x] = M;
  }
}

// ---------------- top-k stage A: 64 blocks, per-block top-20 of 2048 ----------------
__global__ void k_topk_a(const float* __restrict__ defen, float* __restrict__ cand) {
  __shared__ float vals[2048];
  __shared__ float wv[4];
  __shared__ int wi[4];
  const int tid = threadIdx.x;
  const int base = blockIdx.x * 2048;
  for (int i = tid; i < 2048; i += 256) vals[i] = defen[base + i];
  __syncthreads();
  for (int it = 0; it < 20; ++it) {
    float mv = -1e30f; int mi = 1 << 30;
    for (int i = tid; i < 2048; i += 256) {
      float v = vals[i];
      if (v > mv) { mv = v; mi = i; }
    }
#pragma unroll
    for (int off = 1; off < 64; off <<= 1) {
      float ov = __shfl_xor(mv, off); int oi = __shfl_xor(mi, off);
      if (ov > mv || (ov == mv && oi < mi)) { mv = ov; mi = oi; }
    }
    if ((tid & 63) == 0) { wv[tid >> 6] = mv; wi[tid >> 6] = mi; }
    __syncthreads();
    if (tid == 0) {
      float bv = wv[0]; int bi = wi[0];
      for (int q = 1; q < 4; ++q)
        if (wv[q] > bv || (wv[q] == bv && wi[q] < bi)) { bv = wv[q]; bi = wi[q]; }
      cand[blockIdx.x * 20 + it] = bv;
      vals[bi] = -1e30f;
    }
    __syncthreads();
  }
}

// ---------------- top-k stage B: final top-20 of 1280 + R_loss ----------------
__global__ void k_topk_b(const float* __restrict__ cand, const float* __restrict__ msep,
                         float* __restrict__ rloss) {
  __shared__ float vals[1280];
  __shared__ float wv[4];
  __shared__ int wi[4];
  __shared__ float msum[4];
  const int tid = threadIdx.x;
  for (int i = tid; i < 1280; i += 256) vals[i] = cand[i];
  float ms = 0.f;
  for (int i = tid; i < 4096; i += 256) ms += msep[i];
#pragma unroll
  for (int off = 1; off < 64; off <<= 1) ms += __shfl_xor(ms, off);
  if ((tid & 63) == 0) msum[tid >> 6] = ms;
  __syncthreads();
  float sam = 0.f;
  for (int it = 0; it < 20; ++it) {
    float mv = -1e30f; int mi = 1 << 30;
    for (int i = tid; i < 1280; i += 256) {
      float v = vals[i];
      if (v > mv) { mv = v; mi = i; }
    }
#pragma unroll
    for (int off = 1; off < 64; off <<= 1) {
      float ov = __shfl_xor(mv, off); int oi = __shfl_xor(mi, off);
      if (ov > mv || (ov == mv && oi < mi)) { mv = ov; mi = oi; }
    }
    if ((tid & 63) == 0) { wv[tid >> 6] = mv; wi[tid >> 6] = mi; }
    __syncthreads();
    if (tid == 0) {
      float bv = wv[0]; int bi = wi[0];
      for (int q = 1; q < 4; ++q)
        if (wv[q] > bv || (wv[q] == bv && wi[q] < bi)) { bv = wv[q]; bi = wi[q]; }
      sam += bv;
      vals[bi] = -1e30f;
    }
    __syncthreads();
  }
  if (tid == 0) {
    float mse = (msum[0] + msum[1] + msum[2] + msum[3]) / 29360128.f;  // N*D
    rloss[0] = mse + 0.1f * sam;
  }
}

extern "C" void kernel_launch(void* const* d_in, const int* in_sizes, int n_in,
                              void* d_out, int out_size, void* d_ws, size_t ws_size,
                              hipStream_t stream) {
  const float* x    = (const float*)d_in[0];
  const float* dinp = (const float*)d_in[1];
  const float* We1  = (const float*)d_in[2];
  const float* be1  = (const float*)d_in[3];
  const float* We2  = (const float*)d_in[4];
  const float* be2  = (const float*)d_in[5];
  const float* We3  = (const float*)d_in[6];
  const float* be3  = (const float*)d_in[7];
  const float* Wd1  = (const float*)d_in[8];
  const float* bd1  = (const float*)d_in[9];
  const float* Wd2  = (const float*)d_in[10];
  const float* bd2  = (const float*)d_in[11];
  const float* Wd3  = (const float*)d_in[12];
  const float* bd3  = (const float*)d_in[13];

  float* y_out = (float*)d_out;
  float* z_out = y_out + (size_t)NROWS * DDIM;
  float* r_out = z_out + (size_t)NROWS * 4;

  char* ws = (char*)d_ws;
  u16* W1h = (u16*)(ws + OFF_W1H);
  u16* W1l = (u16*)(ws + OFF_W1L);
  u16* W2h = (u16*)(ws + OFF_W2H);
  u16* W2l = (u16*)(ws + OFF_W2L);
  u16* W5h = (u16*)(ws + OFF_W5H);
  u16* W5l = (u16*)(ws + OFF_W5L);
  u16* W6h = (u16*)(ws + OFF_W6H);
  u16* W6l = (u16*)(ws + OFF_W6L);
  float* Cf    = (float*)(ws + OFF_C);
  float* msep  = (float*)(ws + OFF_MSEP);
  float* defen = (float*)(ws + OFF_DEFEN);
  float* cand  = (float*)(ws + OFF_CAND);

  (void)hipFuncSetAttribute((const void*)k_main, hipFuncAttributeMaxDynamicSharedMemorySize, LDS_TOTAL);

  k_prep<<<dim3(256), dim3(256), 0, stream>>>(We1, We2, Wd2, Wd3, dinp,
                                              W1h, W1l, W2h, W2l, W5h, W5l, W6h, W6l, Cf);
  k_main<<<dim3(4096), dim3(256), LDS_TOTAL, stream>>>(x, dinp, be1, be2, be3, bd1, bd2, bd3,
                                                       We3, Wd1, W1h, W1l, W2h, W2l, W5h, W5l,
                                                       W6h, W6l, Cf, y_out, z_out, defen, msep);
  k_topk_a<<<dim3(64), dim3(256), 0, stream>>>(defen, cand);
  k_topk_b<<<dim3(1), dim3(256), 0, stream>>>(cand, msep, r_out);
}